// Round 2
// baseline (839.558 us; speedup 1.0000x reference)
//
#include <hip/hip_runtime.h>
#include <math.h>

#define B_ 16
#define S_ 4096
#define D_ 512
#define L_ 50
#define C_ 8
#define N_ 400   // L_*C_

// ---------------- K1: score_t[b][n][s] = sum_d text[b][s][d] * des[n][d] ----------------
#define MT 256
#define NT 64
#define KT 16

__global__ __launch_bounds__(256) void k1_score(const float* __restrict__ text,
                                                const float* __restrict__ des,
                                                float* __restrict__ score_t) {
    __shared__ float As[KT][MT + 4];   // [k][m]
    __shared__ float Bs[KT][NT + 4];   // [k][n]
    const int ntile = blockIdx.x;      // 0..6
    const int mtile = blockIdx.y;      // 0..255
    const int tid = threadIdx.x;
    const int r0 = mtile * MT;         // global row = b*S + s
    const int n0 = ntile * NT;
    const int tx = tid & 15;           // n = n0 + tx*4 + j
    const int ty = tid >> 4;           // m = ty*16 + i

    float acc[16][4];
    #pragma unroll
    for (int i = 0; i < 16; ++i)
        #pragma unroll
        for (int j = 0; j < 4; ++j) acc[i][j] = 0.f;

    for (int kc = 0; kc < D_; kc += KT) {
        // A tile: 256 rows x 16 k  (1024 float4, 4 per thread)
        #pragma unroll
        for (int i = 0; i < 4; ++i) {
            int p = tid + i * 256;
            int row = p >> 2;
            int kg = (p & 3) * 4;
            float4 v = *(const float4*)&text[(size_t)(r0 + row) * D_ + kc + kg];
            As[kg + 0][row] = v.x;
            As[kg + 1][row] = v.y;
            As[kg + 2][row] = v.z;
            As[kg + 3][row] = v.w;
        }
        // B tile: 64 rows x 16 k (256 float4, 1 per thread)
        {
            int row = tid >> 2;
            int kg = (tid & 3) * 4;
            int gn = n0 + row;
            float4 v = make_float4(0.f, 0.f, 0.f, 0.f);
            if (gn < N_) v = *(const float4*)&des[(size_t)gn * D_ + kc + kg];
            Bs[kg + 0][row] = v.x;
            Bs[kg + 1][row] = v.y;
            Bs[kg + 2][row] = v.z;
            Bs[kg + 3][row] = v.w;
        }
        __syncthreads();
        #pragma unroll
        for (int k = 0; k < KT; ++k) {
            float4 bf = *(const float4*)&Bs[k][tx * 4];
            float bn[4] = {bf.x, bf.y, bf.z, bf.w};
            #pragma unroll
            for (int i4 = 0; i4 < 4; ++i4) {
                float4 af = *(const float4*)&As[k][ty * 16 + i4 * 4];
                float am[4] = {af.x, af.y, af.z, af.w};
                #pragma unroll
                for (int t = 0; t < 4; ++t)
                    #pragma unroll
                    for (int j = 0; j < 4; ++j)
                        acc[i4 * 4 + t][j] += am[t] * bn[j];
            }
        }
        __syncthreads();
    }

    // epilogue: write transposed score_t[b][n][s]
    const int b = r0 >> 12;        // /4096
    const int s0 = (r0 & (S_ - 1)) + ty * 16;
    #pragma unroll
    for (int j = 0; j < 4; ++j) {
        int gn = n0 + tx * 4 + j;
        if (gn < N_) {
            float* dst = &score_t[((size_t)b * N_ + gn) * S_ + s0];
            #pragma unroll
            for (int q = 0; q < 4; ++q) {
                float4 o = make_float4(acc[q * 4 + 0][j], acc[q * 4 + 1][j],
                                       acc[q * 4 + 2][j], acc[q * 4 + 3][j]);
                *(float4*)&dst[q * 4] = o;
            }
        }
    }
}

// ---------------- K2: per (b,l): softmax stats over s for 8 c's, then A[b][l][s] = sum_c alpha ----
__global__ __launch_bounds__(256) void k2_softmax_A(const float* __restrict__ score_t,
                                                    float* __restrict__ A) {
    const int l = blockIdx.x;   // 0..49
    const int b = blockIdx.y;   // 0..15
    const int tid = threadIdx.x;
    __shared__ float rmax[256], rsum[256];
    __shared__ float cmax[8], cinv[8];

    for (int c = 0; c < 8; ++c) {
        const float4* row = (const float4*)(score_t + ((size_t)b * N_ + l * 8 + c) * S_);
        float v[16];
        #pragma unroll
        for (int i = 0; i < 4; ++i) {
            float4 x = row[tid + i * 256];
            v[i * 4 + 0] = x.x; v[i * 4 + 1] = x.y; v[i * 4 + 2] = x.z; v[i * 4 + 3] = x.w;
        }
        float lm = v[0];
        #pragma unroll
        for (int i = 1; i < 16; ++i) lm = fmaxf(lm, v[i]);
        float ls = 0.f;
        #pragma unroll
        for (int i = 0; i < 16; ++i) ls += __expf(v[i] - lm);
        rmax[tid] = lm;
        rsum[tid] = ls;
        __syncthreads();
        for (int off = 128; off > 0; off >>= 1) {
            if (tid < off) {
                float m1 = rmax[tid], m2 = rmax[tid + off];
                float s1 = rsum[tid], s2 = rsum[tid + off];
                float mm = fmaxf(m1, m2);
                rmax[tid] = mm;
                rsum[tid] = s1 * __expf(m1 - mm) + s2 * __expf(m2 - mm);
            }
            __syncthreads();
        }
        if (tid == 0) { cmax[c] = rmax[0]; cinv[c] = 1.f / rsum[0]; }
        __syncthreads();
    }

    // phase 2: A = sum_c exp(score - max_c) * inv_c
    float4* Arow = (float4*)(A + ((size_t)b * L_ + l) * S_);
    #pragma unroll
    for (int i = 0; i < 4; ++i) {
        int p = tid + i * 256;
        float4 a = make_float4(0.f, 0.f, 0.f, 0.f);
        #pragma unroll
        for (int c = 0; c < 8; ++c) {
            const float4* row = (const float4*)(score_t + ((size_t)b * N_ + l * 8 + c) * S_);
            float4 x = row[p];
            float mm = cmax[c], iv = cinv[c];
            a.x += __expf(x.x - mm) * iv;
            a.y += __expf(x.y - mm) * iv;
            a.z += __expf(x.z - mm) * iv;
            a.w += __expf(x.w - mm) * iv;
        }
        Arow[p] = a;
    }
}

// ---------------- K3: m[b][l][d] += sum_s A[b][l][s] * text[b][s][d] ----------------
#define DT3 128
#define ST3 64
#define KSPLIT 8

__global__ __launch_bounds__(256) void k3_mgemm(const float* __restrict__ text,
                                                const float* __restrict__ A,
                                                float* __restrict__ m_out) {
    const int dt = blockIdx.x;        // 0..3
    const int b  = blockIdx.y;        // 0..15
    const int ks = blockIdx.z;        // 0..7
    const int tid = threadIdx.x;
    const int tx = tid & 31;          // d = d0 + tx*4
    const int ty = tid >> 5;          // l = ty + 8*i
    __shared__ float Ts[ST3][DT3 + 4];
    __shared__ float Asb[L_][ST3 + 4];

    const int d0 = dt * DT3;
    const int s_begin = ks * (S_ / KSPLIT);

    float acc[7][4];
    #pragma unroll
    for (int i = 0; i < 7; ++i)
        #pragma unroll
        for (int j = 0; j < 4; ++j) acc[i][j] = 0.f;

    for (int sc = 0; sc < S_ / KSPLIT; sc += ST3) {
        const int s0 = s_begin + sc;
        // text chunk: 64 s x 128 d = 2048 float4 (8 per thread)
        #pragma unroll
        for (int i = 0; i < 8; ++i) {
            int p = tid + i * 256;
            int row = p >> 5;
            int col = (p & 31) * 4;
            float4 v = *(const float4*)&text[((size_t)b * S_ + s0 + row) * D_ + d0 + col];
            *(float4*)&Ts[row][col] = v;
        }
        // A chunk: 50 l x 64 s = 800 float4
        for (int p = tid; p < 800; p += 256) {
            int row = p >> 4;
            int col = (p & 15) * 4;
            float4 v = *(const float4*)&A[((size_t)b * L_ + row) * S_ + s0 + col];
            *(float4*)&Asb[row][col] = v;
        }
        __syncthreads();
        for (int sl = 0; sl < ST3; ++sl) {
            float4 t4 = *(const float4*)&Ts[sl][tx * 4];
            #pragma unroll
            for (int i = 0; i < 6; ++i) {
                float a = Asb[ty + 8 * i][sl];
                acc[i][0] += a * t4.x;
                acc[i][1] += a * t4.y;
                acc[i][2] += a * t4.z;
                acc[i][3] += a * t4.w;
            }
            if (ty < 2) {   // l = ty + 48
                float a = Asb[ty + 48][sl];
                acc[6][0] += a * t4.x;
                acc[6][1] += a * t4.y;
                acc[6][2] += a * t4.z;
                acc[6][3] += a * t4.w;
            }
        }
        __syncthreads();
    }

    #pragma unroll
    for (int i = 0; i < 7; ++i) {
        int l = ty + 8 * i;
        if (l < L_) {
            float* dst = &m_out[((size_t)b * L_ + l) * D_ + d0 + tx * 4];
            atomicAdd(&dst[0], acc[i][0]);
            atomicAdd(&dst[1], acc[i][1]);
            atomicAdd(&dst[2], acc[i][2]);
            atomicAdd(&dst[3], acc[i][3]);
        }
    }
}

// ---------------- K4: des=max_c(label); w=leaky(des@Ww+bw); b=leaky(des@Wb+bb); logits ---------
__global__ __launch_bounds__(256) void k4_final(const float* __restrict__ des,
                                                const float* __restrict__ Ww,
                                                const float* __restrict__ bw,
                                                const float* __restrict__ Wb,
                                                const float* __restrict__ bbv,
                                                const float* __restrict__ m_in,
                                                float* __restrict__ out) {
    const int l = blockIdx.x;
    const int tid = threadIdx.x;
    __shared__ float des_l[D_];
    __shared__ float w_l[D_];
    __shared__ float red[256];
    __shared__ float bl;

    #pragma unroll
    for (int i = 0; i < 2; ++i) {
        int d = tid + i * 256;
        float mx = -INFINITY;
        #pragma unroll
        for (int c = 0; c < 8; ++c)
            mx = fmaxf(mx, des[(size_t)(l * 8 + c) * D_ + d]);
        des_l[d] = mx;
    }
    __syncthreads();

    #pragma unroll
    for (int i = 0; i < 2; ++i) {
        int d = tid + i * 256;
        float s = bw[d];
        #pragma unroll 4
        for (int k = 0; k < D_; ++k)
            s += des_l[k] * Ww[(size_t)k * D_ + d];
        w_l[d] = s > 0.f ? s : 0.01f * s;
    }

    float p = 0.f;
    #pragma unroll
    for (int i = 0; i < 2; ++i) {
        int k = tid + i * 256;
        p += des_l[k] * Wb[k];
    }
    red[tid] = p;
    __syncthreads();
    for (int off = 128; off > 0; off >>= 1) {
        if (tid < off) red[tid] += red[tid + off];
        __syncthreads();
    }
    if (tid == 0) {
        float v = red[0] + bbv[0];
        bl = v > 0.f ? v : 0.01f * v;
    }
    __syncthreads();

    for (int bi = 0; bi < B_; ++bi) {
        float q = 0.f;
        #pragma unroll
        for (int i = 0; i < 2; ++i) {
            int k = tid + i * 256;
            q += m_in[((size_t)bi * L_ + l) * D_ + k] * w_l[k];
        }
        red[tid] = q;
        __syncthreads();
        for (int off = 128; off > 0; off >>= 1) {
            if (tid < off) red[tid] += red[tid + off];
            __syncthreads();
        }
        if (tid == 0) out[bi * L_ + l] = red[0] + bl;
        __syncthreads();
    }
}

extern "C" void kernel_launch(void* const* d_in, const int* in_sizes, int n_in,
                              void* d_out, int out_size, void* d_ws, size_t ws_size,
                              hipStream_t stream) {
    const float* text = (const float*)d_in[0];
    // d_in[1] = text_mask (unused, all-true in reference)
    const float* des  = (const float*)d_in[2];
    const float* Ww   = (const float*)d_in[3];
    const float* bw   = (const float*)d_in[4];
    const float* Wb   = (const float*)d_in[5];
    const float* bbv  = (const float*)d_in[6];
    float* out = (float*)d_out;

    float* score_t = (float*)d_ws;                       // [B][400][S]  f32 = 104.9 MB
    float* A       = score_t + (size_t)B_ * N_ * S_;     // [B][L][S]    f32 = 13.1 MB
    float* m       = A + (size_t)B_ * L_ * S_;           // [B][L][D]    f32 = 1.6 MB

    hipMemsetAsync(m, 0, (size_t)B_ * L_ * D_ * sizeof(float), stream);

    k1_score<<<dim3(7, (B_ * S_) / MT), 256, 0, stream>>>(text, des, score_t);
    k2_softmax_A<<<dim3(L_, B_), 256, 0, stream>>>(score_t, A);
    k3_mgemm<<<dim3(D_ / DT3, B_, KSPLIT), 256, 0, stream>>>(text, A, m);
    k4_final<<<L_, 256, 0, stream>>>(des, Ww, bw, Wb, bbv, m, out);
}

// Round 3
// 655.465 us; speedup vs baseline: 1.2809x; 1.2809x over previous
//
#include <hip/hip_runtime.h>
#include <math.h>

#define B_ 16
#define S_ 4096
#define D_ 512
#define L_ 50
#define C_ 8
#define N_ 400   // L_*C_

typedef __attribute__((ext_vector_type(8))) short bf16x8;
typedef __attribute__((ext_vector_type(4))) float f32x4;

// split fp32 -> bf16 hi (round-nearest) + bf16 lo (residual, truncated)
__device__ __forceinline__ void split_bf16(float x, unsigned short& h, unsigned short& l) {
    unsigned int xb = __float_as_uint(x);
    unsigned int hb = (xb + 0x8000u) & 0xffff0000u;   // rounded-to-nearest-ish bf16
    float lf = x - __uint_as_float(hb);
    h = (unsigned short)(hb >> 16);
    l = (unsigned short)(__float_as_uint(lf) >> 16);
}

// ---------------- K1: score_t[b][n][s] = sum_d text[b][s][d] * des[n][d]  (split-bf16 MFMA) ----
#define BM1 128   // text rows per block
#define BN1 64    // des rows per block
#define KC1 32    // k chunk
#define LDK 40    // padded k stride (ushorts) -> 80 B rows, breaks bank cycling

__global__ __launch_bounds__(256) void k1_score_mfma(const float* __restrict__ text,
                                                     const float* __restrict__ des,
                                                     float* __restrict__ score_t) {
    __shared__ unsigned short th[BM1][LDK];  // text hi
    __shared__ unsigned short tl[BM1][LDK];  // text lo
    __shared__ unsigned short dh[BN1][LDK];  // des hi
    __shared__ unsigned short dl[BN1][LDK];  // des lo

    const int ntile = blockIdx.x;        // 0..6
    const int mtile = blockIdx.y;        // 0..511
    const int tid = threadIdx.x;
    const int r0 = mtile * BM1;          // global text row = b*S + s
    const int n0 = ntile * BN1;
    const int b  = r0 >> 12;
    const int s0 = r0 & (S_ - 1);

    const int wave = tid >> 6;           // 0..3
    const int lane = tid & 63;
    const int wn = wave & 1;             // des half (32 rows)
    const int wm = wave >> 1;            // text half (64 rows)
    const int lrow = lane & 15;
    const int lkg  = lane >> 4;          // 0..3 -> k-offset lkg*8

    f32x4 acc[2][4];
    #pragma unroll
    for (int i = 0; i < 2; ++i)
        #pragma unroll
        for (int j = 0; j < 4; ++j) acc[i][j] = (f32x4){0.f, 0.f, 0.f, 0.f};

    for (int kc = 0; kc < D_; kc += KC1) {
        // ---- stage text: 128 rows x 32 k (1024 float4, 4/thread) ----
        #pragma unroll
        for (int i = 0; i < 4; ++i) {
            int idx = tid + i * 256;            // 0..1023
            int row = idx >> 3;                 // 8 float4 per row
            int kq  = (idx & 7) * 4;
            float4 v = *(const float4*)&text[(size_t)(r0 + row) * D_ + kc + kq];
            unsigned short h0,h1,h2,h3,l0,l1,l2,l3;
            split_bf16(v.x,h0,l0); split_bf16(v.y,h1,l1);
            split_bf16(v.z,h2,l2); split_bf16(v.w,h3,l3);
            ushort4 hv = make_ushort4(h0,h1,h2,h3);
            ushort4 lv = make_ushort4(l0,l1,l2,l3);
            *(ushort4*)&th[row][kq] = hv;
            *(ushort4*)&tl[row][kq] = lv;
        }
        // ---- stage des: 64 rows x 32 k (512 float4, 2/thread), guarded ----
        #pragma unroll
        for (int i = 0; i < 2; ++i) {
            int idx = tid + i * 256;            // 0..511
            int row = idx >> 3;
            int kq  = (idx & 7) * 4;
            int gn  = n0 + row;
            float4 v = make_float4(0.f,0.f,0.f,0.f);
            if (gn < N_) v = *(const float4*)&des[(size_t)gn * D_ + kc + kq];
            unsigned short h0,h1,h2,h3,l0,l1,l2,l3;
            split_bf16(v.x,h0,l0); split_bf16(v.y,h1,l1);
            split_bf16(v.z,h2,l2); split_bf16(v.w,h3,l3);
            *(ushort4*)&dh[row][kq] = make_ushort4(h0,h1,h2,h3);
            *(ushort4*)&dl[row][kq] = make_ushort4(l0,l1,l2,l3);
        }
        __syncthreads();

        // ---- fragments ----
        bf16x8 fdh[2], fdl[2], fth[4], ftl[4];
        #pragma unroll
        for (int nr = 0; nr < 2; ++nr) {
            int row = wn * 32 + nr * 16 + lrow;
            fdh[nr] = *(const bf16x8*)&dh[row][lkg * 8];
            fdl[nr] = *(const bf16x8*)&dl[row][lkg * 8];
        }
        #pragma unroll
        for (int mr = 0; mr < 4; ++mr) {
            int row = wm * 64 + mr * 16 + lrow;
            fth[mr] = *(const bf16x8*)&th[row][lkg * 8];
            ftl[mr] = *(const bf16x8*)&tl[row][lkg * 8];
        }
        // ---- MFMA: A = des (M dim), B = text (N dim) ----
        #pragma unroll
        for (int nr = 0; nr < 2; ++nr)
            #pragma unroll
            for (int mr = 0; mr < 4; ++mr) {
                acc[nr][mr] = __builtin_amdgcn_mfma_f32_16x16x32_bf16(fdh[nr], fth[mr], acc[nr][mr], 0, 0, 0);
                acc[nr][mr] = __builtin_amdgcn_mfma_f32_16x16x32_bf16(fdh[nr], ftl[mr], acc[nr][mr], 0, 0, 0);
                acc[nr][mr] = __builtin_amdgcn_mfma_f32_16x16x32_bf16(fdl[nr], fth[mr], acc[nr][mr], 0, 0, 0);
            }
        __syncthreads();
    }

    // ---- epilogue: C layout col=lane&15 (text/s), row=(lane>>4)*4+reg (des/n) ----
    #pragma unroll
    for (int nr = 0; nr < 2; ++nr) {
        #pragma unroll
        for (int mr = 0; mr < 4; ++mr) {
            int s = s0 + wm * 64 + mr * 16 + (lane & 15);
            #pragma unroll
            for (int r = 0; r < 4; ++r) {
                int n = n0 + wn * 32 + nr * 16 + (lane >> 4) * 4 + r;
                if (n < N_)
                    score_t[((size_t)b * N_ + n) * S_ + s] = acc[nr][mr][r];
            }
        }
    }
}

// ---------------- K2: per (b,l): softmax stats over s for 8 c's, then A[b][l][s] = sum_c alpha ----
__global__ __launch_bounds__(256) void k2_softmax_A(const float* __restrict__ score_t,
                                                    float* __restrict__ A) {
    const int l = blockIdx.x;   // 0..49
    const int b = blockIdx.y;   // 0..15
    const int tid = threadIdx.x;
    __shared__ float rmax[256], rsum[256];
    __shared__ float cmax[8], cinv[8];

    for (int c = 0; c < 8; ++c) {
        const float4* row = (const float4*)(score_t + ((size_t)b * N_ + l * 8 + c) * S_);
        float v[16];
        #pragma unroll
        for (int i = 0; i < 4; ++i) {
            float4 x = row[tid + i * 256];
            v[i * 4 + 0] = x.x; v[i * 4 + 1] = x.y; v[i * 4 + 2] = x.z; v[i * 4 + 3] = x.w;
        }
        float lm = v[0];
        #pragma unroll
        for (int i = 1; i < 16; ++i) lm = fmaxf(lm, v[i]);
        float ls = 0.f;
        #pragma unroll
        for (int i = 0; i < 16; ++i) ls += __expf(v[i] - lm);
        rmax[tid] = lm;
        rsum[tid] = ls;
        __syncthreads();
        for (int off = 128; off > 0; off >>= 1) {
            if (tid < off) {
                float m1 = rmax[tid], m2 = rmax[tid + off];
                float s1 = rsum[tid], s2 = rsum[tid + off];
                float mm = fmaxf(m1, m2);
                rmax[tid] = mm;
                rsum[tid] = s1 * __expf(m1 - mm) + s2 * __expf(m2 - mm);
            }
            __syncthreads();
        }
        if (tid == 0) { cmax[c] = rmax[0]; cinv[c] = 1.f / rsum[0]; }
        __syncthreads();
    }

    // phase 2: A = sum_c exp(score - max_c) * inv_c
    float4* Arow = (float4*)(A + ((size_t)b * L_ + l) * S_);
    #pragma unroll
    for (int i = 0; i < 4; ++i) {
        int p = tid + i * 256;
        float4 a = make_float4(0.f, 0.f, 0.f, 0.f);
        #pragma unroll
        for (int c = 0; c < 8; ++c) {
            const float4* row = (const float4*)(score_t + ((size_t)b * N_ + l * 8 + c) * S_);
            float4 x = row[p];
            float mm = cmax[c], iv = cinv[c];
            a.x += __expf(x.x - mm) * iv;
            a.y += __expf(x.y - mm) * iv;
            a.z += __expf(x.z - mm) * iv;
            a.w += __expf(x.w - mm) * iv;
        }
        Arow[p] = a;
    }
}

// ---------------- K3: m[b][l][d] += sum_s A[b][l][s] * text[b][s][d] ----------------
#define DT3 128
#define ST3 64
#define KSPLIT 8

__global__ __launch_bounds__(256) void k3_mgemm(const float* __restrict__ text,
                                                const float* __restrict__ A,
                                                float* __restrict__ m_out) {
    const int dt = blockIdx.x;        // 0..3
    const int b  = blockIdx.y;        // 0..15
    const int ks = blockIdx.z;        // 0..7
    const int tid = threadIdx.x;
    const int tx = tid & 31;          // d = d0 + tx*4
    const int ty = tid >> 5;          // l = ty + 8*i
    __shared__ float Ts[ST3][DT3 + 4];
    __shared__ float Asb[L_][ST3 + 4];

    const int d0 = dt * DT3;
    const int s_begin = ks * (S_ / KSPLIT);

    float acc[7][4];
    #pragma unroll
    for (int i = 0; i < 7; ++i)
        #pragma unroll
        for (int j = 0; j < 4; ++j) acc[i][j] = 0.f;

    for (int sc = 0; sc < S_ / KSPLIT; sc += ST3) {
        const int s0 = s_begin + sc;
        #pragma unroll
        for (int i = 0; i < 8; ++i) {
            int p = tid + i * 256;
            int row = p >> 5;
            int col = (p & 31) * 4;
            float4 v = *(const float4*)&text[((size_t)b * S_ + s0 + row) * D_ + d0 + col];
            *(float4*)&Ts[row][col] = v;
        }
        for (int p = tid; p < 800; p += 256) {
            int row = p >> 4;
            int col = (p & 15) * 4;
            float4 v = *(const float4*)&A[((size_t)b * L_ + row) * S_ + s0 + col];
            *(float4*)&Asb[row][col] = v;
        }
        __syncthreads();
        for (int sl = 0; sl < ST3; ++sl) {
            float4 t4 = *(const float4*)&Ts[sl][tx * 4];
            #pragma unroll
            for (int i = 0; i < 6; ++i) {
                float a = Asb[ty + 8 * i][sl];
                acc[i][0] += a * t4.x;
                acc[i][1] += a * t4.y;
                acc[i][2] += a * t4.z;
                acc[i][3] += a * t4.w;
            }
            if (ty < 2) {
                float a = Asb[ty + 48][sl];
                acc[6][0] += a * t4.x;
                acc[6][1] += a * t4.y;
                acc[6][2] += a * t4.z;
                acc[6][3] += a * t4.w;
            }
        }
        __syncthreads();
    }

    #pragma unroll
    for (int i = 0; i < 7; ++i) {
        int l = ty + 8 * i;
        if (l < L_) {
            float* dst = &m_out[((size_t)b * L_ + l) * D_ + d0 + tx * 4];
            atomicAdd(&dst[0], acc[i][0]);
            atomicAdd(&dst[1], acc[i][1]);
            atomicAdd(&dst[2], acc[i][2]);
            atomicAdd(&dst[3], acc[i][3]);
        }
    }
}

// ---------------- K4: des=max_c(label); w=leaky(des@Ww+bw); b=leaky(des@Wb+bb); logits ---------
__global__ __launch_bounds__(256) void k4_final(const float* __restrict__ des,
                                                const float* __restrict__ Ww,
                                                const float* __restrict__ bw,
                                                const float* __restrict__ Wb,
                                                const float* __restrict__ bbv,
                                                const float* __restrict__ m_in,
                                                float* __restrict__ out) {
    const int l = blockIdx.x;
    const int tid = threadIdx.x;
    __shared__ float des_l[D_];
    __shared__ float w_l[D_];
    __shared__ float red[256];
    __shared__ float bl;

    #pragma unroll
    for (int i = 0; i < 2; ++i) {
        int d = tid + i * 256;
        float mx = -INFINITY;
        #pragma unroll
        for (int c = 0; c < 8; ++c)
            mx = fmaxf(mx, des[(size_t)(l * 8 + c) * D_ + d]);
        des_l[d] = mx;
    }
    __syncthreads();

    #pragma unroll
    for (int i = 0; i < 2; ++i) {
        int d = tid + i * 256;
        float s = bw[d];
        #pragma unroll 4
        for (int k = 0; k < D_; ++k)
            s += des_l[k] * Ww[(size_t)k * D_ + d];
        w_l[d] = s > 0.f ? s : 0.01f * s;
    }

    float p = 0.f;
    #pragma unroll
    for (int i = 0; i < 2; ++i) {
        int k = tid + i * 256;
        p += des_l[k] * Wb[k];
    }
    red[tid] = p;
    __syncthreads();
    for (int off = 128; off > 0; off >>= 1) {
        if (tid < off) red[tid] += red[tid + off];
        __syncthreads();
    }
    if (tid == 0) {
        float v = red[0] + bbv[0];
        bl = v > 0.f ? v : 0.01f * v;
    }
    __syncthreads();

    for (int bi = 0; bi < B_; ++bi) {
        float q = 0.f;
        #pragma unroll
        for (int i = 0; i < 2; ++i) {
            int k = tid + i * 256;
            q += m_in[((size_t)bi * L_ + l) * D_ + k] * w_l[k];
        }
        red[tid] = q;
        __syncthreads();
        for (int off = 128; off > 0; off >>= 1) {
            if (tid < off) red[tid] += red[tid + off];
            __syncthreads();
        }
        if (tid == 0) out[bi * L_ + l] = red[0] + bl;
        __syncthreads();
    }
}

extern "C" void kernel_launch(void* const* d_in, const int* in_sizes, int n_in,
                              void* d_out, int out_size, void* d_ws, size_t ws_size,
                              hipStream_t stream) {
    const float* text = (const float*)d_in[0];
    // d_in[1] = text_mask (unused, all-true in reference)
    const float* des  = (const float*)d_in[2];
    const float* Ww   = (const float*)d_in[3];
    const float* bw   = (const float*)d_in[4];
    const float* Wb   = (const float*)d_in[5];
    const float* bbv  = (const float*)d_in[6];
    float* out = (float*)d_out;

    float* score_t = (float*)d_ws;                       // [B][400][S]  f32 = 104.9 MB
    float* A       = score_t + (size_t)B_ * N_ * S_;     // [B][L][S]    f32 = 13.1 MB
    float* m       = A + (size_t)B_ * L_ * S_;           // [B][L][D]    f32 = 1.6 MB

    hipMemsetAsync(m, 0, (size_t)B_ * L_ * D_ * sizeof(float), stream);

    k1_score_mfma<<<dim3(7, (B_ * S_) / BM1), 256, 0, stream>>>(text, des, score_t);
    k2_softmax_A<<<dim3(L_, B_), 256, 0, stream>>>(score_t, A);
    k3_mgemm<<<dim3(D_ / DT3, B_, KSPLIT), 256, 0, stream>>>(text, A, m);
    k4_final<<<L_, 256, 0, stream>>>(des, Ww, bw, Wb, bbv, m, out);
}

// Round 7
// 540.477 us; speedup vs baseline: 1.5534x; 1.2128x over previous
//
#include <hip/hip_runtime.h>
#include <math.h>

#define B_ 16
#define S_ 4096
#define D_ 512
#define L_ 50
#define C_ 8
#define N_ 400   // L_*C_

typedef __attribute__((ext_vector_type(8))) short bf16x8;
typedef __attribute__((ext_vector_type(4))) float f32x4;

// split fp32 -> bf16 hi (round-nearest) + bf16 lo (residual, round-nearest)
__device__ __forceinline__ void split_bf16(float x, unsigned short& h, unsigned short& l) {
    unsigned int xb = __float_as_uint(x);
    unsigned int hb = (xb + 0x8000u) & 0xffff0000u;
    float lf = x - __uint_as_float(hb);
    h = (unsigned short)(hb >> 16);
    l = (unsigned short)((__float_as_uint(lf) + 0x8000u) >> 16);
}

// ---------------- K1: score_t[b][n][s] = sum_d text[b][s][d] * des[n][d]  (split-bf16 MFMA) ----
#define BM1 128   // text rows per block
#define BN1 80    // des rows per block (5 tiles x 80 = 400 exact)
#define KC1 32    // k chunk
#define LDK 40    // padded k stride (ushorts)

__global__ __launch_bounds__(256) void k1_score_mfma(const float* __restrict__ text,
                                                     const float* __restrict__ des,
                                                     float* __restrict__ score_t) {
    __shared__ unsigned short th[BM1][LDK];
    __shared__ unsigned short tl[BM1][LDK];
    __shared__ unsigned short dh[BN1][LDK];
    __shared__ unsigned short dl[BN1][LDK];

    // bijective XCD swizzle: 2560 wgs, each XCD gets 64 consecutive mtiles x all 5 ntiles
    const int nwg = gridDim.x * gridDim.y;            // 2560
    int wg = blockIdx.y * gridDim.x + blockIdx.x;
    int q = nwg >> 3;                                 // 320
    int sw = (wg & 7) * q + (wg >> 3);
    const int ntile = sw % 5;
    const int mtile = sw / 5;

    const int tid = threadIdx.x;
    const int r0 = mtile * BM1;          // global text row = b*S + s
    const int n0 = ntile * BN1;
    const int b  = r0 >> 12;
    const int s0 = r0 & (S_ - 1);

    const int wave = tid >> 6;           // 0..3 -> 32 text rows each
    const int lane = tid & 63;
    const int lrow = lane & 15;
    const int lkg  = lane >> 4;          // k-offset lkg*8

    f32x4 acc[5][2];
    #pragma unroll
    for (int i = 0; i < 5; ++i)
        #pragma unroll
        for (int j = 0; j < 2; ++j) acc[i][j] = (f32x4){0.f, 0.f, 0.f, 0.f};

    for (int kc = 0; kc < D_; kc += KC1) {
        // stage text: 128 rows x 32 k (1024 float4, 4/thread)
        #pragma unroll
        for (int i = 0; i < 4; ++i) {
            int idx = tid + i * 256;
            int row = idx >> 3;
            int kq  = (idx & 7) * 4;
            float4 v = *(const float4*)&text[(size_t)(r0 + row) * D_ + kc + kq];
            unsigned short h0,h1,h2,h3,l0,l1,l2,l3;
            split_bf16(v.x,h0,l0); split_bf16(v.y,h1,l1);
            split_bf16(v.z,h2,l2); split_bf16(v.w,h3,l3);
            *(ushort4*)&th[row][kq] = make_ushort4(h0,h1,h2,h3);
            *(ushort4*)&tl[row][kq] = make_ushort4(l0,l1,l2,l3);
        }
        // stage des: 80 rows x 32 k (640 float4)
        for (int p = tid; p < 640; p += 256) {
            int row = p >> 3;
            int kq  = (p & 7) * 4;
            float4 v = *(const float4*)&des[(size_t)(n0 + row) * D_ + kc + kq];
            unsigned short h0,h1,h2,h3,l0,l1,l2,l3;
            split_bf16(v.x,h0,l0); split_bf16(v.y,h1,l1);
            split_bf16(v.z,h2,l2); split_bf16(v.w,h3,l3);
            *(ushort4*)&dh[row][kq] = make_ushort4(h0,h1,h2,h3);
            *(ushort4*)&dl[row][kq] = make_ushort4(l0,l1,l2,l3);
        }
        __syncthreads();

        bf16x8 fdh[5], fdl[5], fth[2], ftl[2];
        #pragma unroll
        for (int nf = 0; nf < 5; ++nf) {
            int row = nf * 16 + lrow;
            fdh[nf] = *(const bf16x8*)&dh[row][lkg * 8];
            fdl[nf] = *(const bf16x8*)&dl[row][lkg * 8];
        }
        #pragma unroll
        for (int mf = 0; mf < 2; ++mf) {
            int row = wave * 32 + mf * 16 + lrow;
            fth[mf] = *(const bf16x8*)&th[row][lkg * 8];
            ftl[mf] = *(const bf16x8*)&tl[row][lkg * 8];
        }
        #pragma unroll
        for (int nf = 0; nf < 5; ++nf)
            #pragma unroll
            for (int mf = 0; mf < 2; ++mf) {
                acc[nf][mf] = __builtin_amdgcn_mfma_f32_16x16x32_bf16(fdh[nf], fth[mf], acc[nf][mf], 0, 0, 0);
                acc[nf][mf] = __builtin_amdgcn_mfma_f32_16x16x32_bf16(fdh[nf], ftl[mf], acc[nf][mf], 0, 0, 0);
                acc[nf][mf] = __builtin_amdgcn_mfma_f32_16x16x32_bf16(fdl[nf], fth[mf], acc[nf][mf], 0, 0, 0);
            }
        __syncthreads();
    }

    // epilogue: C layout col(lane&15)=text/s, row((lane>>4)*4+r)=des/n
    #pragma unroll
    for (int nf = 0; nf < 5; ++nf) {
        #pragma unroll
        for (int mf = 0; mf < 2; ++mf) {
            int s = s0 + wave * 32 + mf * 16 + (lane & 15);
            #pragma unroll
            for (int r = 0; r < 4; ++r) {
                int n = n0 + nf * 16 + (lane >> 4) * 4 + r;
                score_t[((size_t)b * N_ + n) * S_ + s] = acc[nf][mf][r];
            }
        }
    }
}

// ---------------- K2: wave-per-c softmax stats, then A[b][l][s] = sum_c alpha --------------
__global__ __launch_bounds__(512) void k2_softmax_A(const float* __restrict__ score_t,
                                                    float* __restrict__ A) {
    const int l = blockIdx.x;   // 0..49
    const int b = blockIdx.y;   // 0..15
    const int tid = threadIdx.x;
    const int c = tid >> 6;     // wave id = class
    const int lane = tid & 63;
    __shared__ float cm[8], ci[8];

    const float4* row = (const float4*)(score_t + ((size_t)b * N_ + l * 8 + c) * S_);
    float v[64];
    #pragma unroll
    for (int i = 0; i < 16; ++i) {
        float4 x = row[lane + 64 * i];
        v[4*i] = x.x; v[4*i+1] = x.y; v[4*i+2] = x.z; v[4*i+3] = x.w;
    }
    float lm = v[0];
    #pragma unroll
    for (int i = 1; i < 64; ++i) lm = fmaxf(lm, v[i]);
    #pragma unroll
    for (int off = 32; off > 0; off >>= 1) lm = fmaxf(lm, __shfl_xor(lm, off, 64));
    float ls = 0.f;
    #pragma unroll
    for (int i = 0; i < 64; ++i) ls += __expf(v[i] - lm);
    #pragma unroll
    for (int off = 32; off > 0; off >>= 1) ls += __shfl_xor(ls, off, 64);
    if (lane == 0) { cm[c] = lm; ci[c] = 1.f / ls; }
    __syncthreads();

    float4* Arow = (float4*)(A + ((size_t)b * L_ + l) * S_);
    #pragma unroll
    for (int h = 0; h < 2; ++h) {
        int p = tid + h * 512;
        float4 a = make_float4(0.f, 0.f, 0.f, 0.f);
        #pragma unroll
        for (int cc = 0; cc < 8; ++cc) {
            const float4* r2 = (const float4*)(score_t + ((size_t)b * N_ + l * 8 + cc) * S_);
            float4 x = r2[p];
            float mm = cm[cc], iv = ci[cc];
            a.x += __expf(x.x - mm) * iv;
            a.y += __expf(x.y - mm) * iv;
            a.z += __expf(x.z - mm) * iv;
            a.w += __expf(x.w - mm) * iv;
        }
        Arow[p] = a;
    }
}

// ---------------- K3: mp[ks][b][l][d] = sum_{s in chunk ks} A[b][l][s] * text[b][s][d] -----
#define DT3 128
#define ST3 64
#define KSPLIT 8

__global__ __launch_bounds__(256) void k3_mgemm(const float* __restrict__ text,
                                                const float* __restrict__ A,
                                                float* __restrict__ mp) {
    const int dt = blockIdx.x;        // 0..3
    const int b  = blockIdx.y;        // 0..15
    const int ks = blockIdx.z;        // 0..7
    const int tid = threadIdx.x;
    const int tx = tid & 31;          // d = d0 + tx*4
    const int ty = tid >> 5;          // l = ty + 8*i
    __shared__ float Ts[ST3][DT3 + 4];
    __shared__ float Asb[L_][ST3 + 4];

    const int d0 = dt * DT3;
    const int s_begin = ks * (S_ / KSPLIT);

    float acc[7][4];
    #pragma unroll
    for (int i = 0; i < 7; ++i)
        #pragma unroll
        for (int j = 0; j < 4; ++j) acc[i][j] = 0.f;

    for (int sc = 0; sc < S_ / KSPLIT; sc += ST3) {
        const int s0 = s_begin + sc;
        #pragma unroll
        for (int i = 0; i < 8; ++i) {
            int p = tid + i * 256;
            int row = p >> 5;
            int col = (p & 31) * 4;
            float4 v = *(const float4*)&text[((size_t)b * S_ + s0 + row) * D_ + d0 + col];
            *(float4*)&Ts[row][col] = v;
        }
        for (int p = tid; p < 800; p += 256) {
            int row = p >> 4;
            int col = (p & 15) * 4;
            float4 v = *(const float4*)&A[((size_t)b * L_ + row) * S_ + s0 + col];
            *(float4*)&Asb[row][col] = v;
        }
        __syncthreads();
        for (int sl = 0; sl < ST3; ++sl) {
            float4 t4 = *(const float4*)&Ts[sl][tx * 4];
            #pragma unroll
            for (int i = 0; i < 6; ++i) {
                float a = Asb[ty + 8 * i][sl];
                acc[i][0] += a * t4.x;
                acc[i][1] += a * t4.y;
                acc[i][2] += a * t4.z;
                acc[i][3] += a * t4.w;
            }
            if (ty < 2) {
                float a = Asb[ty + 48][sl];
                acc[6][0] += a * t4.x;
                acc[6][1] += a * t4.y;
                acc[6][2] += a * t4.z;
                acc[6][3] += a * t4.w;
            }
        }
        __syncthreads();
    }

    // plain stores to per-ks partials (no atomics)
    #pragma unroll
    for (int i = 0; i < 7; ++i) {
        int l = ty + 8 * i;
        if (l < L_) {
            float* dst = &mp[(((size_t)ks * B_ + b) * L_ + l) * D_ + d0 + tx * 4];
            *(float4*)dst = make_float4(acc[i][0], acc[i][1], acc[i][2], acc[i][3]);
        }
    }
}

// ---------------- K4a: des=max_c(label); w=leaky(des@Ww+bw); b=leaky(des@Wb+bb) ------------
__global__ __launch_bounds__(512) void k4a(const float* __restrict__ des,
                                           const float* __restrict__ Ww,
                                           const float* __restrict__ bw,
                                           const float* __restrict__ Wb,
                                           const float* __restrict__ bbv,
                                           float* __restrict__ w_buf,
                                           float* __restrict__ bvec) {
    const int l = blockIdx.x;
    const int tid = threadIdx.x;  // = d
    __shared__ float des_l[D_];
    __shared__ float red[512];

    float mx = -INFINITY;
    #pragma unroll
    for (int c = 0; c < 8; ++c)
        mx = fmaxf(mx, des[(size_t)(l * 8 + c) * D_ + tid]);
    des_l[tid] = mx;
    __syncthreads();

    float s = bw[tid];
    #pragma unroll 4
    for (int k = 0; k < D_; ++k)
        s += des_l[k] * Ww[(size_t)k * D_ + tid];
    w_buf[(size_t)l * D_ + tid] = s > 0.f ? s : 0.01f * s;

    red[tid] = des_l[tid] * Wb[tid];
    __syncthreads();
    for (int off = 256; off > 0; off >>= 1) {
        if (tid < off) red[tid] += red[tid + off];
        __syncthreads();
    }
    if (tid == 0) {
        float v = red[0] + bbv[0];
        bvec[l] = v > 0.f ? v : 0.01f * v;
    }
}

// ---------------- K4b: logits[b][l] = sum_d (sum_ks mp)·w + b ------------------------------
__global__ __launch_bounds__(64) void k4b(const float* __restrict__ mp,
                                          const float* __restrict__ w_buf,
                                          const float* __restrict__ bvec,
                                          float* __restrict__ out) {
    const int l = blockIdx.x;
    const int b = blockIdx.y;
    const int lane = threadIdx.x;
    float acc = 0.f;
    #pragma unroll
    for (int i = 0; i < 8; ++i) {
        int d = lane + 64 * i;
        float msum = 0.f;
        #pragma unroll
        for (int ks = 0; ks < KSPLIT; ++ks)
            msum += mp[(((size_t)ks * B_ + b) * L_ + l) * D_ + d];
        acc += msum * w_buf[(size_t)l * D_ + d];
    }
    #pragma unroll
    for (int off = 32; off > 0; off >>= 1) acc += __shfl_xor(acc, off, 64);
    if (lane == 0) out[b * L_ + l] = acc + bvec[l];
}

extern "C" void kernel_launch(void* const* d_in, const int* in_sizes, int n_in,
                              void* d_out, int out_size, void* d_ws, size_t ws_size,
                              hipStream_t stream) {
    const float* text = (const float*)d_in[0];
    const float* des  = (const float*)d_in[2];
    const float* Ww   = (const float*)d_in[3];
    const float* bw   = (const float*)d_in[4];
    const float* Wb   = (const float*)d_in[5];
    const float* bbv  = (const float*)d_in[6];
    float* out = (float*)d_out;

    float* score_t = (float*)d_ws;                       // [B][400][S]  104.9 MB
    float* A       = score_t + (size_t)B_ * N_ * S_;     // [B][L][S]    13.1 MB
    float* w_buf   = A + (size_t)B_ * L_ * S_;           // [L][D]       0.1 MB
    float* bvec    = w_buf + (size_t)L_ * D_;            // [L]
    float* mp      = score_t;                            // [8][B][L][D] aliases dead score_t

    k1_score_mfma<<<dim3(5, (B_ * S_) / BM1), 256, 0, stream>>>(text, des, score_t);
    k2_softmax_A<<<dim3(L_, B_), 512, 0, stream>>>(score_t, A);
    k3_mgemm<<<dim3(D_ / DT3, B_, KSPLIT), 256, 0, stream>>>(text, A, mp);
    k4a<<<L_, 512, 0, stream>>>(des, Ww, bw, Wb, bbv, w_buf, bvec);
    k4b<<<dim3(L_, B_), 64, 0, stream>>>(mp, w_buf, bvec, out);
}

// Round 9
// 518.396 us; speedup vs baseline: 1.6195x; 1.0426x over previous
//
#include <hip/hip_runtime.h>
#include <math.h>

#define B_ 16
#define S_ 4096
#define D_ 512
#define L_ 50
#define C_ 8
#define N_ 400   // L_*C_

typedef __attribute__((ext_vector_type(8))) short bf16x8;
typedef __attribute__((ext_vector_type(4))) float f32x4;
typedef unsigned short u16;

// split fp32 -> bf16 hi (round-nearest) + bf16 lo (residual, round-nearest)
__device__ __forceinline__ void split_bf16(float x, unsigned short& h, unsigned short& l) {
    unsigned int xb = __float_as_uint(x);
    unsigned int hb = (xb + 0x8000u) & 0xffff0000u;
    float lf = x - __uint_as_float(hb);
    h = (unsigned short)(hb >> 16);
    l = (unsigned short)((__float_as_uint(lf) + 0x8000u) >> 16);
}

// ---------------- K0: pre-convert fp32 -> bf16 hi/lo arrays --------------------------------
__global__ __launch_bounds__(256) void k0_text(const float* __restrict__ x,
                                               u16* __restrict__ hi, u16* __restrict__ lo) {
    const size_t n4 = (size_t)B_ * S_ * D_ / 4;   // 8,388,608 float4
    for (size_t i = (size_t)blockIdx.x * 256 + threadIdx.x; i < n4; i += (size_t)gridDim.x * 256) {
        float4 v = ((const float4*)x)[i];
        unsigned short h0,h1,h2,h3,l0,l1,l2,l3;
        split_bf16(v.x,h0,l0); split_bf16(v.y,h1,l1);
        split_bf16(v.z,h2,l2); split_bf16(v.w,h3,l3);
        ((ushort4*)hi)[i] = make_ushort4(h0,h1,h2,h3);
        ((ushort4*)lo)[i] = make_ushort4(l0,l1,l2,l3);
    }
}

__global__ __launch_bounds__(256) void k0_des(const float* __restrict__ x,
                                              u16* __restrict__ hi, u16* __restrict__ lo) {
    const int i = blockIdx.x * 256 + threadIdx.x;   // 51200 float4
    if (i < N_ * D_ / 4) {
        float4 v = ((const float4*)x)[i];
        unsigned short h0,h1,h2,h3,l0,l1,l2,l3;
        split_bf16(v.x,h0,l0); split_bf16(v.y,h1,l1);
        split_bf16(v.z,h2,l2); split_bf16(v.w,h3,l3);
        ((ushort4*)hi)[i] = make_ushort4(h0,h1,h2,h3);
        ((ushort4*)lo)[i] = make_ushort4(l0,l1,l2,l3);
    }
}

// ---------------- K1 v2: score_t from pre-converted bf16 hi/lo (reg-staged, prefetched) ----
#define BM1 128
#define BN1 80
#define KC1 32
#define LDK 40
#define NCHUNK 16   // D_/KC1

__global__ __launch_bounds__(256) void k1_score_v2(const u16* __restrict__ th_g,
                                                   const u16* __restrict__ tl_g,
                                                   const u16* __restrict__ dh_g,
                                                   const u16* __restrict__ dl_g,
                                                   float* __restrict__ score_t) {
    __shared__ u16 th[BM1][LDK];
    __shared__ u16 tl[BM1][LDK];
    __shared__ u16 dh[BN1][LDK];
    __shared__ u16 dl[BN1][LDK];

    const int nwg = gridDim.x * gridDim.y;            // 2560
    int wg = blockIdx.y * gridDim.x + blockIdx.x;
    int q = nwg >> 3;
    int sw = (wg & 7) * q + (wg >> 3);
    const int ntile = sw % 5;
    const int mtile = sw / 5;

    const int tid = threadIdx.x;
    const int r0 = mtile * BM1;
    const int n0 = ntile * BN1;
    const int b  = r0 >> 12;
    const int s0 = r0 & (S_ - 1);

    const int wave = tid >> 6;
    const int lane = tid & 63;
    const int lrow = lane & 15;
    const int lkg  = lane >> 4;

    f32x4 acc[5][2];
    #pragma unroll
    for (int i = 0; i < 5; ++i)
        #pragma unroll
        for (int j = 0; j < 2; ++j) acc[i][j] = (f32x4){0.f, 0.f, 0.f, 0.f};

    ushort4 rth[4], rtl[4], rdh[3], rdl[3];

    auto load_chunk = [&](int kc) {
        #pragma unroll
        for (int i = 0; i < 4; ++i) {
            int idx = tid + i * 256;
            int row = idx >> 3;
            int kq  = (idx & 7) * 4;
            size_t g = (size_t)(r0 + row) * D_ + kc + kq;
            rth[i] = *(const ushort4*)&th_g[g];
            rtl[i] = *(const ushort4*)&tl_g[g];
        }
        #pragma unroll
        for (int i = 0; i < 3; ++i) {
            int p = tid + i * 256;
            if (p < 640) {
                int row = p >> 3;
                int kq  = (p & 7) * 4;
                size_t g = (size_t)(n0 + row) * D_ + kc + kq;
                rdh[i] = *(const ushort4*)&dh_g[g];
                rdl[i] = *(const ushort4*)&dl_g[g];
            }
        }
    };
    auto write_chunk = [&]() {
        #pragma unroll
        for (int i = 0; i < 4; ++i) {
            int idx = tid + i * 256;
            int row = idx >> 3;
            int kq  = (idx & 7) * 4;
            *(ushort4*)&th[row][kq] = rth[i];
            *(ushort4*)&tl[row][kq] = rtl[i];
        }
        #pragma unroll
        for (int i = 0; i < 3; ++i) {
            int p = tid + i * 256;
            if (p < 640) {
                int row = p >> 3;
                int kq  = (p & 7) * 4;
                *(ushort4*)&dh[row][kq] = rdh[i];
                *(ushort4*)&dl[row][kq] = rdl[i];
            }
        }
    };

    load_chunk(0);

    for (int ck = 0; ck < NCHUNK; ++ck) {
        __syncthreads();                 // previous chunk's frag reads complete
        write_chunk();
        __syncthreads();
        if (ck + 1 < NCHUNK) load_chunk((ck + 1) * KC1);   // in flight under frags+MFMA

        bf16x8 fdh[5], fdl[5], fth[2], ftl[2];
        #pragma unroll
        for (int nf = 0; nf < 5; ++nf) {
            int row = nf * 16 + lrow;
            fdh[nf] = *(const bf16x8*)&dh[row][lkg * 8];
            fdl[nf] = *(const bf16x8*)&dl[row][lkg * 8];
        }
        #pragma unroll
        for (int mf = 0; mf < 2; ++mf) {
            int row = wave * 32 + mf * 16 + lrow;
            fth[mf] = *(const bf16x8*)&th[row][lkg * 8];
            ftl[mf] = *(const bf16x8*)&tl[row][lkg * 8];
        }
        #pragma unroll
        for (int nf = 0; nf < 5; ++nf)
            #pragma unroll
            for (int mf = 0; mf < 2; ++mf) {
                acc[nf][mf] = __builtin_amdgcn_mfma_f32_16x16x32_bf16(fdh[nf], fth[mf], acc[nf][mf], 0, 0, 0);
                acc[nf][mf] = __builtin_amdgcn_mfma_f32_16x16x32_bf16(fdh[nf], ftl[mf], acc[nf][mf], 0, 0, 0);
                acc[nf][mf] = __builtin_amdgcn_mfma_f32_16x16x32_bf16(fdl[nf], fth[mf], acc[nf][mf], 0, 0, 0);
            }
    }

    #pragma unroll
    for (int nf = 0; nf < 5; ++nf) {
        #pragma unroll
        for (int mf = 0; mf < 2; ++mf) {
            int s = s0 + wave * 32 + mf * 16 + (lane & 15);
            #pragma unroll
            for (int r = 0; r < 4; ++r) {
                int n = n0 + nf * 16 + (lane >> 4) * 4 + r;
                score_t[((size_t)b * N_ + n) * S_ + s] = acc[nf][mf][r];
            }
        }
    }
}

// ---------------- K1 fallback (round-7 proven, in-loop convert) — used if ws too small -----
__global__ __launch_bounds__(256) void k1_score_conv(const float* __restrict__ text,
                                                     const float* __restrict__ des,
                                                     float* __restrict__ score_t) {
    __shared__ u16 th[BM1][LDK];
    __shared__ u16 tl[BM1][LDK];
    __shared__ u16 dh[BN1][LDK];
    __shared__ u16 dl[BN1][LDK];

    const int nwg = gridDim.x * gridDim.y;
    int wg = blockIdx.y * gridDim.x + blockIdx.x;
    int q = nwg >> 3;
    int sw = (wg & 7) * q + (wg >> 3);
    const int ntile = sw % 5;
    const int mtile = sw / 5;

    const int tid = threadIdx.x;
    const int r0 = mtile * BM1;
    const int n0 = ntile * BN1;
    const int b  = r0 >> 12;
    const int s0 = r0 & (S_ - 1);

    const int wave = tid >> 6;
    const int lane = tid & 63;
    const int lrow = lane & 15;
    const int lkg  = lane >> 4;

    f32x4 acc[5][2];
    #pragma unroll
    for (int i = 0; i < 5; ++i)
        #pragma unroll
        for (int j = 0; j < 2; ++j) acc[i][j] = (f32x4){0.f, 0.f, 0.f, 0.f};

    for (int kc = 0; kc < D_; kc += KC1) {
        #pragma unroll
        for (int i = 0; i < 4; ++i) {
            int idx = tid + i * 256;
            int row = idx >> 3;
            int kq  = (idx & 7) * 4;
            float4 v = *(const float4*)&text[(size_t)(r0 + row) * D_ + kc + kq];
            unsigned short h0,h1,h2,h3,l0,l1,l2,l3;
            split_bf16(v.x,h0,l0); split_bf16(v.y,h1,l1);
            split_bf16(v.z,h2,l2); split_bf16(v.w,h3,l3);
            *(ushort4*)&th[row][kq] = make_ushort4(h0,h1,h2,h3);
            *(ushort4*)&tl[row][kq] = make_ushort4(l0,l1,l2,l3);
        }
        for (int p = tid; p < 640; p += 256) {
            int row = p >> 3;
            int kq  = (p & 7) * 4;
            float4 v = *(const float4*)&des[(size_t)(n0 + row) * D_ + kc + kq];
            unsigned short h0,h1,h2,h3,l0,l1,l2,l3;
            split_bf16(v.x,h0,l0); split_bf16(v.y,h1,l1);
            split_bf16(v.z,h2,l2); split_bf16(v.w,h3,l3);
            *(ushort4*)&dh[row][kq] = make_ushort4(h0,h1,h2,h3);
            *(ushort4*)&dl[row][kq] = make_ushort4(l0,l1,l2,l3);
        }
        __syncthreads();

        bf16x8 fdh[5], fdl[5], fth[2], ftl[2];
        #pragma unroll
        for (int nf = 0; nf < 5; ++nf) {
            int row = nf * 16 + lrow;
            fdh[nf] = *(const bf16x8*)&dh[row][lkg * 8];
            fdl[nf] = *(const bf16x8*)&dl[row][lkg * 8];
        }
        #pragma unroll
        for (int mf = 0; mf < 2; ++mf) {
            int row = wave * 32 + mf * 16 + lrow;
            fth[mf] = *(const bf16x8*)&th[row][lkg * 8];
            ftl[mf] = *(const bf16x8*)&tl[row][lkg * 8];
        }
        #pragma unroll
        for (int nf = 0; nf < 5; ++nf)
            #pragma unroll
            for (int mf = 0; mf < 2; ++mf) {
                acc[nf][mf] = __builtin_amdgcn_mfma_f32_16x16x32_bf16(fdh[nf], fth[mf], acc[nf][mf], 0, 0, 0);
                acc[nf][mf] = __builtin_amdgcn_mfma_f32_16x16x32_bf16(fdh[nf], ftl[mf], acc[nf][mf], 0, 0, 0);
                acc[nf][mf] = __builtin_amdgcn_mfma_f32_16x16x32_bf16(fdl[nf], fth[mf], acc[nf][mf], 0, 0, 0);
            }
        __syncthreads();
    }

    #pragma unroll
    for (int nf = 0; nf < 5; ++nf) {
        #pragma unroll
        for (int mf = 0; mf < 2; ++mf) {
            int s = s0 + wave * 32 + mf * 16 + (lane & 15);
            #pragma unroll
            for (int r = 0; r < 4; ++r) {
                int n = n0 + nf * 16 + (lane >> 4) * 4 + r;
                score_t[((size_t)b * N_ + n) * S_ + s] = acc[nf][mf][r];
            }
        }
    }
}

// ---------------- K2: wave-per-c softmax stats, then A[b][l][s] = sum_c alpha --------------
__global__ __launch_bounds__(512) void k2_softmax_A(const float* __restrict__ score_t,
                                                    float* __restrict__ A) {
    const int l = blockIdx.x;
    const int b = blockIdx.y;
    const int tid = threadIdx.x;
    const int c = tid >> 6;
    const int lane = tid & 63;
    __shared__ float cm[8], ci[8];

    const float4* row = (const float4*)(score_t + ((size_t)b * N_ + l * 8 + c) * S_);
    float v[64];
    #pragma unroll
    for (int i = 0; i < 16; ++i) {
        float4 x = row[lane + 64 * i];
        v[4*i] = x.x; v[4*i+1] = x.y; v[4*i+2] = x.z; v[4*i+3] = x.w;
    }
    float lm = v[0];
    #pragma unroll
    for (int i = 1; i < 64; ++i) lm = fmaxf(lm, v[i]);
    #pragma unroll
    for (int off = 32; off > 0; off >>= 1) lm = fmaxf(lm, __shfl_xor(lm, off, 64));
    float ls = 0.f;
    #pragma unroll
    for (int i = 0; i < 64; ++i) ls += __expf(v[i] - lm);
    #pragma unroll
    for (int off = 32; off > 0; off >>= 1) ls += __shfl_xor(ls, off, 64);
    if (lane == 0) { cm[c] = lm; ci[c] = 1.f / ls; }
    __syncthreads();

    float4* Arow = (float4*)(A + ((size_t)b * L_ + l) * S_);
    #pragma unroll
    for (int h = 0; h < 2; ++h) {
        int p = tid + h * 512;
        float4 a = make_float4(0.f, 0.f, 0.f, 0.f);
        #pragma unroll
        for (int cc = 0; cc < 8; ++cc) {
            const float4* r2 = (const float4*)(score_t + ((size_t)b * N_ + l * 8 + cc) * S_);
            float4 x = r2[p];
            float mm = cm[cc], iv = ci[cc];
            a.x += __expf(x.x - mm) * iv;
            a.y += __expf(x.y - mm) * iv;
            a.z += __expf(x.z - mm) * iv;
            a.w += __expf(x.w - mm) * iv;
        }
        Arow[p] = a;
    }
}

// ---------------- K3: mp[ks][b][l][d] = sum_{s in chunk ks} A[b][l][s] * text[b][s][d] -----
#define DT3 128
#define ST3 64
#define KSPLIT 8

__global__ __launch_bounds__(256) void k3_mgemm(const float* __restrict__ text,
                                                const float* __restrict__ A,
                                                float* __restrict__ mp) {
    const int dt = blockIdx.x;
    const int b  = blockIdx.y;
    const int ks = blockIdx.z;
    const int tid = threadIdx.x;
    const int tx = tid & 31;
    const int ty = tid >> 5;
    __shared__ float Ts[ST3][DT3 + 4];
    __shared__ float Asb[L_][ST3 + 4];

    const int d0 = dt * DT3;
    const int s_begin = ks * (S_ / KSPLIT);

    float acc[7][4];
    #pragma unroll
    for (int i = 0; i < 7; ++i)
        #pragma unroll
        for (int j = 0; j < 4; ++j) acc[i][j] = 0.f;

    for (int sc = 0; sc < S_ / KSPLIT; sc += ST3) {
        const int s0 = s_begin + sc;
        #pragma unroll
        for (int i = 0; i < 8; ++i) {
            int p = tid + i * 256;
            int row = p >> 5;
            int col = (p & 31) * 4;
            float4 v = *(const float4*)&text[((size_t)b * S_ + s0 + row) * D_ + d0 + col];
            *(float4*)&Ts[row][col] = v;
        }
        for (int p = tid; p < 800; p += 256) {
            int row = p >> 4;
            int col = (p & 15) * 4;
            float4 v = *(const float4*)&A[((size_t)b * L_ + row) * S_ + s0 + col];
            *(float4*)&Asb[row][col] = v;
        }
        __syncthreads();
        for (int sl = 0; sl < ST3; ++sl) {
            float4 t4 = *(const float4*)&Ts[sl][tx * 4];
            #pragma unroll
            for (int i = 0; i < 6; ++i) {
                float a = Asb[ty + 8 * i][sl];
                acc[i][0] += a * t4.x;
                acc[i][1] += a * t4.y;
                acc[i][2] += a * t4.z;
                acc[i][3] += a * t4.w;
            }
            if (ty < 2) {
                float a = Asb[ty + 48][sl];
                acc[6][0] += a * t4.x;
                acc[6][1] += a * t4.y;
                acc[6][2] += a * t4.z;
                acc[6][3] += a * t4.w;
            }
        }
        __syncthreads();
    }

    #pragma unroll
    for (int i = 0; i < 7; ++i) {
        int l = ty + 8 * i;
        if (l < L_) {
            float* dst = &mp[(((size_t)ks * B_ + b) * L_ + l) * D_ + d0 + tx * 4];
            *(float4*)dst = make_float4(acc[i][0], acc[i][1], acc[i][2], acc[i][3]);
        }
    }
}

// ---------------- K4a / K4b ----------------------------------------------------------------
__global__ __launch_bounds__(512) void k4a(const float* __restrict__ des,
                                           const float* __restrict__ Ww,
                                           const float* __restrict__ bw,
                                           const float* __restrict__ Wb,
                                           const float* __restrict__ bbv,
                                           float* __restrict__ w_buf,
                                           float* __restrict__ bvec) {
    const int l = blockIdx.x;
    const int tid = threadIdx.x;
    __shared__ float des_l[D_];
    __shared__ float red[512];

    float mx = -INFINITY;
    #pragma unroll
    for (int c = 0; c < 8; ++c)
        mx = fmaxf(mx, des[(size_t)(l * 8 + c) * D_ + tid]);
    des_l[tid] = mx;
    __syncthreads();

    float s = bw[tid];
    #pragma unroll 4
    for (int k = 0; k < D_; ++k)
        s += des_l[k] * Ww[(size_t)k * D_ + tid];
    w_buf[(size_t)l * D_ + tid] = s > 0.f ? s : 0.01f * s;

    red[tid] = des_l[tid] * Wb[tid];
    __syncthreads();
    for (int off = 256; off > 0; off >>= 1) {
        if (tid < off) red[tid] += red[tid + off];
        __syncthreads();
    }
    if (tid == 0) {
        float v = red[0] + bbv[0];
        bvec[l] = v > 0.f ? v : 0.01f * v;
    }
}

__global__ __launch_bounds__(64) void k4b(const float* __restrict__ mp,
                                          const float* __restrict__ w_buf,
                                          const float* __restrict__ bvec,
                                          float* __restrict__ out) {
    const int l = blockIdx.x;
    const int b = blockIdx.y;
    const int lane = threadIdx.x;
    float acc = 0.f;
    #pragma unroll
    for (int i = 0; i < 8; ++i) {
        int d = lane + 64 * i;
        float msum = 0.f;
        #pragma unroll
        for (int ks = 0; ks < KSPLIT; ++ks)
            msum += mp[(((size_t)ks * B_ + b) * L_ + l) * D_ + d];
        acc += msum * w_buf[(size_t)l * D_ + d];
    }
    #pragma unroll
    for (int off = 32; off > 0; off >>= 1) acc += __shfl_xor(acc, off, 64);
    if (lane == 0) out[b * L_ + l] = acc + bvec[l];
}

extern "C" void kernel_launch(void* const* d_in, const int* in_sizes, int n_in,
                              void* d_out, int out_size, void* d_ws, size_t ws_size,
                              hipStream_t stream) {
    const float* text = (const float*)d_in[0];
    const float* des  = (const float*)d_in[2];
    const float* Ww   = (const float*)d_in[3];
    const float* bw   = (const float*)d_in[4];
    const float* Wb   = (const float*)d_in[5];
    const float* bbv  = (const float*)d_in[6];
    float* out = (float*)d_out;

    float* ws = (float*)d_ws;
    float* score_t = ws;                                     // [B][400][S]  104.9 MB
    float* A       = score_t + (size_t)B_ * N_ * S_;         // [B][L][S]    13.1 MB
    float* w_buf   = A + (size_t)B_ * L_ * S_;               // [L][D]
    float* bvec    = w_buf + (size_t)L_ * D_;                // [L] (padded 64)
    float* mp      = score_t;                                // [8][B][L][D] aliases dead score_t

    u16* th_g = (u16*)(bvec + 64);                           // [B*S][D] bf16 hi   67.1 MB
    u16* tl_g = th_g + (size_t)B_ * S_ * D_;                 // lo                67.1 MB
    u16* dh_g = tl_g + (size_t)B_ * S_ * D_;                 // [400][D] hi
    u16* dl_g = dh_g + (size_t)N_ * D_;                      // lo
    size_t needed = (size_t)((char*)(dl_g + (size_t)N_ * D_) - (char*)d_ws);

    if (ws_size >= needed) {
        k0_text<<<2048, 256, 0, stream>>>(text, th_g, tl_g);
        k0_des<<<200, 256, 0, stream>>>(des, dh_g, dl_g);
        k1_score_v2<<<dim3(5, (B_ * S_) / BM1), 256, 0, stream>>>(th_g, tl_g, dh_g, dl_g, score_t);
    } else {
        k1_score_conv<<<dim3(5, (B_ * S_) / BM1), 256, 0, stream>>>(text, des, score_t);
    }
    k2_softmax_A<<<dim3(L_, B_), 512, 0, stream>>>(score_t, A);
    k3_mgemm<<<dim3(D_ / DT3, B_, KSPLIT), 256, 0, stream>>>(text, A, mp);
    k4a<<<L_, 512, 0, stream>>>(des, Ww, bw, Wb, bbv, w_buf, bvec);
    k4b<<<dim3(L_, B_), 64, 0, stream>>>(mp, w_buf, bvec, out);
}